// Round 10
// baseline (486.773 us; speedup 1.0000x reference)
//
#include <hip/hip_runtime.h>
#include <hip/hip_bf16.h>

// EncoderBlock: LN1 -> MHA -> +res -> LN2 -> MLP(GELU exact) -> +res
// B=16 S=512 E=1024 F=4096 H=16 D=64, fp32 in/out, bf16 MFMA internally.
//
// R15: de-fence gemm8_bt. R14 A/B proved barrier COUNT is null (4ph vs 2ph
//   both 116.8 on the same node class). Remaining mechanism: every phase
//   variant fenced reads from MFMA via lgkmcnt(0)+sched_barrier(0), which
//   defeats the compiler's fine-grained lgkmcnt interleave (the m97/874TF
//   mechanism; our own unfenced gemm_bt gets 615+TF the same way). New
//   loop: per K-tile {stage B(t+1); [kk=0,1: 12 ds_reads + 32 MFMA,
//   NO fences]; barrier; stage A(t+2); vmcnt(4); barrier} = 2 barriers.
//   vmcnt invariant unchanged (boundary vmcnt(4) drains A(t+1),B(t+1),
//   leaves A(t+2); vmcnt(0) at NT-2). Per-acc kk0->kk1 order unchanged ->
//   bit-identical output. gemm8 is 1 block/CU so no occupancy downside.
//   Predict: w1 116.8 -> ~90-100 (116-class), MfmaUtil 24->30+, VGPR ~200.
//   w1 within 3% of 117 refutes -> structural ceiling, revert & hold.
// Node forensics: judge node class by w1 hbm_gbps (>=1220 healthy;
//   ~700 = throttled = void), not host-side preloaded/push times.
// Ledger (116-class): w1 116.8 | w2 ~110 | QK ~60-85 | attn ~55 | V ~34 |
//   wo ~34 | ln 20 | prep 15 | gaps ~25.
//
// ws layout (bytes):
//   0        wqkvT  [3072][1024] bf16   6 MB   (wq^T|wk^T|wv^T)
//   6 MB     woT    [1024][1024] bf16   2 MB
//   8 MB     w1T    [4096][1024] bf16   8 MB
//   16 MB    w2T    [1024][4096] bf16   8 MB
//   24 MB    qk     [8192][2048] bf16  32 MB   (Q|K)   -> later x fp32 [8192][1024] 32 MB
//   56 MB    Vt     [256][64][512] bf16 16 MB          -> later y_ln bf16 16 MB
//   72 MB    abuf   [8192][1024] bf16  16 MB (ln1/attn)-> later h bf16 [8192][4096] 64 MB (72..136)
//   136 MB   bqkv   [3072] f32  12 KB

typedef __bf16 bf16x8 __attribute__((ext_vector_type(8)));
typedef __bf16 bf16x4 __attribute__((ext_vector_type(4)));
typedef float  f32x4  __attribute__((ext_vector_type(4)));

#define EPI_QKV  0
#define EPI_RES  1
#define EPI_GELU 2
#define EPI_V    3

__device__ __forceinline__ void async_copy16(const void* g, void* l) {
  __builtin_amdgcn_global_load_lds((const __attribute__((address_space(1))) void*)g,
                                   (__attribute__((address_space(3))) void*)l, 16, 0, 0);
}

// ---------------- fused weight prep: 6 transposes (fp32->bf16, [K][N]->[N][K]) + bias concat
__global__ __launch_bounds__(256) void prep_weights(
    const float* __restrict__ wq, const float* __restrict__ wk,
    const float* __restrict__ wv, const float* __restrict__ wo,
    const float* __restrict__ w1, const float* __restrict__ w2,
    const float* __restrict__ bq, const float* __restrict__ bk,
    const float* __restrict__ bv,
    __bf16* __restrict__ wqkvT, __bf16* __restrict__ woT,
    __bf16* __restrict__ w1T, __bf16* __restrict__ w2T, float* __restrict__ bqkv) {
  const int bid = blockIdx.x;
  if (bid >= 12288) { // 12 bias blocks -> 3072 elements
    const int i = (bid - 12288) * 256 + threadIdx.x;
    bqkv[i] = (i < 1024) ? bq[i] : ((i < 2048) ? bk[i - 1024] : bv[i - 2048]);
    return;
  }
  const float* in;
  __bf16* out;
  int K, N, tile;
  if (bid < 4096) { // four 1024x1024 weights, 1024 tiles (32x32) each
    const int w = bid >> 10;
    tile = bid & 1023;
    in = (w == 0) ? wq : (w == 1) ? wk : (w == 2) ? wv : wo;
    out = (w == 3) ? woT : (wqkvT + (size_t)w * 1024 * 1024);
    K = 1024; N = 1024;
  } else if (bid < 8192) { tile = bid - 4096; in = w1; out = w1T; K = 1024; N = 4096; }
  else                   { tile = bid - 8192; in = w2; out = w2T; K = 4096; N = 1024; }
  const int ntx = N >> 5;
  const int bx = tile % ntx, by = tile / ntx;
  const int n0 = bx * 32, k0 = by * 32;

  __shared__ float tilebuf[32][33];
  const int tx = threadIdx.x & 31, ty = threadIdx.x >> 5; // 32x8
#pragma unroll
  for (int i = 0; i < 4; i++)
    tilebuf[ty + i * 8][tx] = in[(size_t)(k0 + ty + i * 8) * N + n0 + tx];
  __syncthreads();
#pragma unroll
  for (int i = 0; i < 4; i++)
    out[(size_t)(n0 + ty + i * 8) * K + k0 + tx] = (__bf16)tilebuf[tx][ty + i * 8];
}

// ---------------- layernorm: one block per row (E=1024, 256 thr * float4)
__device__ __forceinline__ float block_sum(float v, float* red) {
#pragma unroll
  for (int off = 32; off; off >>= 1) v += __shfl_down(v, off);
  const int w = threadIdx.x >> 6;
  __syncthreads();
  if ((threadIdx.x & 63) == 0) red[w] = v;
  __syncthreads();
  return red[0] + red[1] + red[2] + red[3];
}

__global__ __launch_bounds__(256) void ln_kernel(const float* __restrict__ x,
                                                 const float* __restrict__ g,
                                                 const float* __restrict__ bta,
                                                 __bf16* __restrict__ out) {
  __shared__ float red[8];
  const int row = blockIdx.x, t = threadIdx.x;
  const float4 v = ((const float4*)(x + (size_t)row * 1024))[t];
  float s = v.x + v.y + v.z + v.w;
  s = block_sum(s, red);
  const float mean = s * (1.0f / 1024.0f);
  const float d0 = v.x - mean, d1 = v.y - mean, d2 = v.z - mean, d3 = v.w - mean;
  float vs = d0 * d0 + d1 * d1 + d2 * d2 + d3 * d3;
  vs = block_sum(vs, red);
  const float rstd = rsqrtf(vs * (1.0f / 1024.0f) + 1e-5f);
  const float4 gg = ((const float4*)g)[t];
  const float4 bb = ((const float4*)bta)[t];
  bf16x4 o;
  o[0] = (__bf16)(d0 * rstd * gg.x + bb.x);
  o[1] = (__bf16)(d1 * rstd * gg.y + bb.y);
  o[2] = (__bf16)(d2 * rstd * gg.z + bb.z);
  o[3] = (__bf16)(d3 * rstd * gg.w + bb.w);
  ((bf16x4*)out)[(size_t)row * 256 + t] = o;
}

// ---------------- GEMM 128x128 (R5-exact): C[8192][N] = A(bf16) * Bt^T + bias
// Single-buffered 32 KiB LDS -> ~3.4 blocks/CU; cross-block TLP hides the
// staging drain. XOR-swizzled LDS (0 conflicts), 16x16x32 MFMA, (256,2).
template <int EPI>
__global__ __launch_bounds__(256, 2) void gemm_bt(const __bf16* __restrict__ A,
                                                  const __bf16* __restrict__ Bt,
                                                  const float* __restrict__ bias,
                                                  const float* __restrict__ res,
                                                  void* __restrict__ out,
                                                  void* __restrict__ out2,
                                                  int N, int K) {
  __shared__ __bf16 lA[128 * 64];
  __shared__ __bf16 lB[128 * 64];
  const int t = threadIdx.x;
  const int wave = t >> 6, lane = t & 63;
  const int lm = lane & 15, lq = lane >> 4;

  // XCD-aware tile mapping (Mtiles = 64, divisible by 8)
  const int Ntiles = gridDim.x;
  const int flat = blockIdx.y * Ntiles + blockIdx.x;
  const int xcd = flat & 7;
  const int local = flat >> 3;
  const int tn = local % Ntiles;
  const int tm = (local / Ntiles) * 8 + xcd;
  const int m0 = tm * 128, n0 = tn * 128;
  const int wm = (wave & 1) * 64, wn = (wave >> 1) * 64;

  f32x4 acc[4][4] = {};

  // staging: thread t covers rows {srow+32i}; LDS slot (t%8) holds global
  // chunk (t%8)^(srow&7)  (XOR swizzle on the SOURCE; async dest stays
  // lane-contiguous as global_load_lds requires).
  const int srow = t >> 3, sslot = t & 7;
  const int schunk = sslot ^ (srow & 7);
  const __bf16* aSrc = A + (size_t)(m0 + srow) * K + schunk * 8;
  const __bf16* bSrc = Bt + (size_t)(n0 + srow) * K + schunk * 8;

  for (int k0 = 0; k0 < K; k0 += 64) {
#pragma unroll
    for (int i = 0; i < 4; i++) {
      async_copy16(aSrc + (size_t)(i * 32) * K, lA + i * 2048 + t * 8);
      async_copy16(bSrc + (size_t)(i * 32) * K, lB + i * 2048 + t * 8);
    }
    aSrc += 64; bSrc += 64;
    __syncthreads();
#pragma unroll
    for (int kk = 0; kk < 2; kk++) {
      bf16x8 af[4], bf[4];
      const int slot = (kk * 4 + lq) ^ (lm & 7); // frag row&7 == lm&7
#pragma unroll
      for (int i = 0; i < 4; i++) {
        af[i] = *(const bf16x8*)&lA[(wm + i * 16 + lm) * 64 + slot * 8];
        bf[i] = *(const bf16x8*)&lB[(wn + i * 16 + lm) * 64 + slot * 8];
      }
#pragma unroll
      for (int mi = 0; mi < 4; mi++)
#pragma unroll
        for (int ni = 0; ni < 4; ni++)
          acc[mi][ni] = __builtin_amdgcn_mfma_f32_16x16x32_bf16(af[mi], bf[ni], acc[mi][ni], 0, 0, 0);
    }
    __syncthreads();
  }

  // epilogue. C/D layout: col = lane&15, row = (lane>>4)*4 + reg  [m89/m91]
#pragma unroll
  for (int mi = 0; mi < 4; mi++) {
    const int gr = m0 + wm + mi * 16 + lq * 4;
#pragma unroll
    for (int ni = 0; ni < 4; ni++) {
      const int gc = n0 + wn + ni * 16 + lm;
      const float bv = bias[gc];
#pragma unroll
      for (int r = 0; r < 4; r++) {
        float v = acc[mi][ni][r] + bv;
        const int row = gr + r;
        if (EPI == EPI_GELU) {
          v = 0.5f * v * (1.0f + erff(v * 0.70710678118654752f));
          ((__bf16*)out)[(size_t)row * N + gc] = (__bf16)v;
        } else if (EPI == EPI_RES) {
          ((float*)out)[(size_t)row * N + gc] = v + res[(size_t)row * N + gc];
        } else if (EPI == EPI_V) { // V -> Vt[b][h][d][s]; gc in 0..1023
          const int d = gc & 63, hh = gc >> 6;
          const int bb = row >> 9, ss = row & 511;
          ((__bf16*)out2)[(((size_t)bb * 16 + hh) * 64 + d) * 512 + ss] = (__bf16)v;
        } else { // EPI_QKV: Q|K -> qk[8192][2048]; V -> Vt[b][h][d][s]
          if (gc < 2048) {
            ((__bf16*)out)[(size_t)row * 2048 + gc] = (__bf16)v;
          } else {
            const int d = gc & 63, hh = (gc - 2048) >> 6;
            const int bb = row >> 9, ss = row & 511;
            ((__bf16*)out2)[(((size_t)bb * 16 + hh) * 64 + d) * 512 + ss] = (__bf16)v;
          }
        }
      }
    }
  }
}

// ---------------- GEMM 256x256, minimal-sync double-buffered (R15). 512 thr /
// 8 waves (2Mx4N), wave tile 128x64, LDS 128 KiB. Per K-tile:
//   stage B(t+1) -> other buf; [kk=0,1: 12 ds_reads + 32 MFMA, NO fences --
//   compiler emits fine-grained lgkmcnt interleave (m97 mechanism)];
//   barrier (all waves' reads of buf(t) complete, since every read is
//   consumed by an MFMA before the barrier); stage A(t+2) -> buf(t) A-half;
//   vmcnt(4) (drains A(t+1),B(t+1), leaves A(t+2)); barrier.
// 2 barriers/K-tile. vmcnt(0) only at NT-2. Per-acc kk order unchanged.
template <int EPI>
__global__ __launch_bounds__(512, 2) void gemm8_bt(const __bf16* __restrict__ A,
                                                   const __bf16* __restrict__ Bt,
                                                   const float* __restrict__ bias,
                                                   void* __restrict__ out,
                                                   void* __restrict__ out2,
                                                   int N, int K) {
  __shared__ __bf16 lA[2 * 256 * 64];
  __shared__ __bf16 lB[2 * 256 * 64];
  const int t = threadIdx.x;
  const int wave = t >> 6, lane = t & 63;
  const int lm = lane & 15, lq = lane >> 4, sw = lm & 7;
  const int wm = wave >> 2, wn = wave & 3;

  const int Ntiles = gridDim.x;
  const int flat = blockIdx.y * Ntiles + blockIdx.x;
  const int xcd = flat & 7;
  const int local = flat >> 3;
  const int tn = local % Ntiles;
  const int tm = (local / Ntiles) * 8 + xcd;
  const int m0 = tm * 256, n0 = tn * 256;

  const int NT = K >> 6;

  const int srow = t >> 3;
  const int schunk = (t & 7) ^ (srow & 7);
  const __bf16* aBase = A + (size_t)(m0 + srow) * K + schunk * 8;
  const __bf16* bBase = Bt + (size_t)(n0 + srow) * K + schunk * 8;
  __bf16* ldA = lA + t * 8;
  __bf16* ldB = lB + t * 8;

  auto stage = [&](int h) {
    if (h >= 4 * NT) return;
    const int tau = h >> 2, type = h & 3, hf = type & 1;
    const size_t roff = (size_t)(hf * 128) * K + (size_t)tau * 64;
    const int loff = (tau & 1) * 16384 + hf * 8192;
    if (type < 2) {
      async_copy16(aBase + roff, ldA + loff);
      async_copy16(aBase + roff + (size_t)64 * K, ldA + loff + 4096);
    } else {
      async_copy16(bBase + roff, ldB + loff);
      async_copy16(bBase + roff + (size_t)64 * K, ldB + loff + 4096);
    }
  };

  f32x4 acc[8][4] = {};

  // prologue: tile0 fully + A(1); vmcnt(4) leaves A(1) in flight
  for (int h = 0; h < 6; ++h) stage(h);
  asm volatile("s_waitcnt vmcnt(4)" ::: "memory");
  __builtin_amdgcn_s_barrier();

  for (int tt = 0; tt < NT; ++tt) {
    const __bf16* bufA = lA + (tt & 1) * 16384;
    const __bf16* bufB = lB + (tt & 1) * 16384;

    // stage B(t+1) into the other buffer (WAR-safe: its last readers
    // finished before tile t-1's boundary barrier)
    stage(4 * tt + 6);
    stage(4 * tt + 7);

    __builtin_amdgcn_s_setprio(1);
#pragma unroll
    for (int kk = 0; kk < 2; ++kk) {
      bf16x8 af[8], bf[4];
#pragma unroll
      for (int ni = 0; ni < 4; ++ni)
        bf[ni] = *(const bf16x8*)&bufB[(wn * 64 + ni * 16 + lm) * 64 +
                                        (((kk * 4 + lq) ^ sw) * 8)];
#pragma unroll
      for (int mi = 0; mi < 8; ++mi)
        af[mi] = *(const bf16x8*)&bufA[(wm * 128 + mi * 16 + lm) * 64 +
                                        (((kk * 4 + lq) ^ sw) * 8)];
#pragma unroll
      for (int mi = 0; mi < 8; ++mi)
#pragma unroll
        for (int ni = 0; ni < 4; ++ni)
          acc[mi][ni] = __builtin_amdgcn_mfma_f32_16x16x32_bf16(af[mi], bf[ni], acc[mi][ni], 0, 0, 0);
    }
    __builtin_amdgcn_s_setprio(0);

    // every ds_read above is consumed by an MFMA (compiler-inserted lgkmcnt)
    // -> at this barrier all reads of buf(t) have completed.
    __builtin_amdgcn_s_barrier();

    if (tt < NT - 1) {
      stage(4 * tt + 8); // A(t+2) -> current (now-idle) A buffer
      stage(4 * tt + 9);
      if (tt == NT - 2) asm volatile("s_waitcnt vmcnt(0)" ::: "memory");
      else              asm volatile("s_waitcnt vmcnt(4)" ::: "memory");
      __builtin_amdgcn_s_barrier();
    }
  }

  // epilogue. C/D layout: col = lane&15, row = (lane>>4)*4 + reg
#pragma unroll
  for (int mi = 0; mi < 8; ++mi) {
    const int gr = m0 + wm * 128 + mi * 16 + lq * 4;
#pragma unroll
    for (int ni = 0; ni < 4; ++ni) {
      const int gc = n0 + wn * 64 + ni * 16 + lm;
      const float bv = bias[gc];
#pragma unroll
      for (int r = 0; r < 4; ++r) {
        float v = acc[mi][ni][r] + bv;
        const int row = gr + r;
        if (EPI == EPI_GELU) {
          v = 0.5f * v * (1.0f + erff(v * 0.70710678118654752f));
          ((__bf16*)out)[(size_t)row * N + gc] = (__bf16)v;
        } else { // EPI_QKV here: used with N=2048 (Q|K only) -> gc < 2048
          if (gc < 2048) {
            ((__bf16*)out)[(size_t)row * 2048 + gc] = (__bf16)v;
          } else {
            const int d = gc & 63, hh = (gc - 2048) >> 6;
            const int bb = row >> 9, ss = row & 511;
            ((__bf16*)out2)[(((size_t)bb * 16 + hh) * 64 + d) * 512 + ss] = (__bf16)v;
          }
        }
      }
    }
  }
}

// ---------------- flash attention (R10 + T5 setprio): 512 blocks (2/CU),
// block = (b, h, 256 q-rows), 4 waves x 64 q-rows (4 static groups of 16).
// K/V double-buffered (80 KiB LDS), counted vmcnt(8) staging.
__global__ __launch_bounds__(256, 2) void attn_kernel(const __bf16* __restrict__ qk,
                                                      const __bf16* __restrict__ Vt,
                                                      __bf16* __restrict__ outA) {
  __shared__ __bf16 lK[2][128 * 64];  // [key][d], 16B chunks XOR'd by key&7
  __shared__ __bf16 lV[2][64 * 128];  // [d][key], 16B chunks XOR'd by d&7
  __shared__ __bf16 lP[4][16 * 128];  // per-wave P, chunks XOR'd by q&7
  const int t = threadIdx.x, wave = t >> 6, lane = t & 63;
  const int lm = lane & 15, lq = lane >> 4;
  const int sw = lm & 7;
  const int flat = blockIdx.x;
  const int xcd = flat & 7, local = flat >> 3;
  const int qt = local & 1;
  const int bh = xcd * 32 + (local >> 1);
  const int h = bh & 15, b = bh >> 4;
  const int qbase = qt * 256 + wave * 64; // block covers 256 q-rows; wave 64

  // Q A-operand frags for 4 groups of 16 rows
  bf16x8 aq[4][2];
#pragma unroll
  for (int qg = 0; qg < 4; qg++) {
    const size_t qrow = (size_t)(b * 512 + qbase + qg * 16 + lm) * 2048 + h * 64;
    aq[qg][0] = *(const bf16x8*)&qk[qrow + lq * 8];
    aq[qg][1] = *(const bf16x8*)&qk[qrow + 32 + lq * 8];
  }

  float mrow[4][4], lrow[4][4];
  f32x4 o[4][4] = {};
#pragma unroll
  for (int qg = 0; qg < 4; qg++)
#pragma unroll
    for (int r = 0; r < 4; r++) { mrow[qg][r] = -3e38f; lrow[qg][r] = 0.f; }

  const int krow = t >> 3;
  const int kchunk = (t & 7) ^ (krow & 7);
  const __bf16* kSrc = qk + (size_t)(b * 512 + krow) * 2048 + 1024 + h * 64 + kchunk * 8;
  const int vrow = t >> 4;
  const int vchunk = (t & 15) ^ (vrow & 7);
  const __bf16* vSrc = Vt + ((size_t)bh * 64 + vrow) * 512 + vchunk * 8;

  auto stage = [&](int kt) {
    __bf16* dK = &lK[kt & 1][t * 8];
    __bf16* dV = &lV[kt & 1][t * 8];
#pragma unroll
    for (int i = 0; i < 4; i++) {
      async_copy16(kSrc + (size_t)(kt * 128 + i * 32) * 2048, dK + i * 2048);
      async_copy16(vSrc + kt * 128 + (size_t)(i * 16) * 512, dV + i * 2048);
    }
  };

  stage(0);
  for (int kt = 0; kt < 4; kt++) {
    if (kt < 3) {
      stage(kt + 1); // other buffer; its readers finished before last iter's end barrier
      asm volatile("s_waitcnt vmcnt(8)" ::: "memory"); // kt's 8 loads done; kt+1's in flight
    } else {
      asm volatile("s_waitcnt vmcnt(0)" ::: "memory");
    }
    __builtin_amdgcn_s_barrier(); // all waves' kt loads landed
    const __bf16* bK = lK[kt & 1];
    const __bf16* bV = lV[kt & 1];

#pragma unroll
    for (int qg = 0; qg < 4; qg++) {
      // S = Q K^T  (16 q x 128 keys)
      f32x4 s[8];
      __builtin_amdgcn_s_setprio(1);
#pragma unroll
      for (int ni = 0; ni < 8; ni++) {
        bf16x8 bk0 = *(const bf16x8*)&bK[(ni * 16 + lm) * 64 + ((lq ^ sw) * 8)];
        bf16x8 bk1 = *(const bf16x8*)&bK[(ni * 16 + lm) * 64 + (((4 + lq) ^ sw) * 8)];
        f32x4 z = {};
        z = __builtin_amdgcn_mfma_f32_16x16x32_bf16(aq[qg][0], bk0, z, 0, 0, 0);
        z = __builtin_amdgcn_mfma_f32_16x16x32_bf16(aq[qg][1], bk1, z, 0, 0, 0);
        s[ni] = z;
      }
      __builtin_amdgcn_s_setprio(0);
#pragma unroll
      for (int ni = 0; ni < 8; ni++)
#pragma unroll
        for (int r = 0; r < 4; r++) s[ni][r] *= 0.125f; // 1/sqrt(64)

      // online softmax; 16 lanes (one quad-row group) share each row
      float mnew[4], alpha[4];
#pragma unroll
      for (int r = 0; r < 4; r++) {
        float mx = s[0][r];
#pragma unroll
        for (int ni = 1; ni < 8; ni++) mx = fmaxf(mx, s[ni][r]);
#pragma unroll
        for (int off = 1; off < 16; off <<= 1) mx = fmaxf(mx, __shfl_xor(mx, off));
        mnew[r] = fmaxf(mrow[qg][r], mx);
        alpha[r] = __expf(mrow[qg][r] - mnew[r]);
        mrow[qg][r] = mnew[r];
      }
      float rs[4] = {0.f, 0.f, 0.f, 0.f};
#pragma unroll
      for (int ni = 0; ni < 8; ni++)
#pragma unroll
        for (int r = 0; r < 4; r++) {
          const float p = __expf(s[ni][r] - mnew[r]);
          s[ni][r] = p;
          rs[r] += p;
        }
#pragma unroll
      for (int r = 0; r < 4; r++) {
#pragma unroll
        for (int off = 1; off < 16; off <<= 1) rs[r] += __shfl_xor(rs[r], off);
        lrow[qg][r] = lrow[qg][r] * alpha[r] + rs[r];
      }

      // P: C-layout -> A-operand layout via per-wave LDS round trip, XOR'd by q&7
#pragma unroll
      for (int ni = 0; ni < 8; ni++) {
        const int chunk = ni * 2 + (lm >> 3);
#pragma unroll
        for (int r = 0; r < 4; r++) {
          const int q = lq * 4 + r;
          lP[wave][q * 128 + ((chunk ^ (q & 7)) * 8) + (lm & 7)] = (__bf16)s[ni][r];
        }
      }
      asm volatile("s_waitcnt lgkmcnt(0)" ::: "memory");
      bf16x8 ap[4];
#pragma unroll
      for (int kc = 0; kc < 4; kc++)
        ap[kc] = *(const bf16x8*)&lP[wave][lm * 128 + (((kc * 4 + lq) ^ sw) * 8)];

#pragma unroll
      for (int di = 0; di < 4; di++)
#pragma unroll
        for (int r = 0; r < 4; r++) o[qg][di][r] *= alpha[r];

      // O += P V ; B-operand n = d (lV[d][key], key contiguous, XOR'd by d&7)
      __builtin_amdgcn_s_setprio(1);
#pragma unroll
      for (int di = 0; di < 4; di++) {
#pragma unroll
        for (int kc = 0; kc < 4; kc++) {
          bf16x8 bv = *(const bf16x8*)&bV[(di * 16 + lm) * 128 + (((kc * 4 + lq) ^ sw) * 8)];
          o[qg][di] = __builtin_amdgcn_mfma_f32_16x16x32_bf16(ap[kc], bv, o[qg][di], 0, 0, 0);
        }
      }
      __builtin_amdgcn_s_setprio(0);
    }
    __builtin_amdgcn_s_barrier(); // all reads of buf[kt&1] done before next stage overwrites
  }

#pragma unroll
  for (int qg = 0; qg < 4; qg++)
#pragma unroll
    for (int di = 0; di < 4; di++)
#pragma unroll
      for (int r = 0; r < 4; r++) {
        const float v = o[qg][di][r] / lrow[qg][r];
        outA[(size_t)(b * 512 + qbase + qg * 16 + lq * 4 + r) * 1024 + h * 64 + di * 16 + lm] = (__bf16)v;
      }
}

extern "C" void kernel_launch(void* const* d_in, const int* in_sizes, int n_in,
                              void* d_out, int out_size, void* d_ws, size_t ws_size,
                              hipStream_t stream) {
  const float* input = (const float*)d_in[0];
  const float* ln1_g = (const float*)d_in[1];
  const float* ln1_b = (const float*)d_in[2];
  const float* wq = (const float*)d_in[3];
  const float* bq = (const float*)d_in[4];
  const float* wk = (const float*)d_in[5];
  const float* bk = (const float*)d_in[6];
  const float* wv = (const float*)d_in[7];
  const float* bv = (const float*)d_in[8];
  const float* wo = (const float*)d_in[9];
  const float* bo = (const float*)d_in[10];
  const float* ln2_g = (const float*)d_in[11];
  const float* ln2_b = (const float*)d_in[12];
  const float* w1 = (const float*)d_in[13];
  const float* b1 = (const float*)d_in[14];
  const float* w2 = (const float*)d_in[15];
  const float* b2 = (const float*)d_in[16];

  char* ws = (char*)d_ws;
  __bf16* wqkvT = (__bf16*)(ws + 0);
  __bf16* woT   = (__bf16*)(ws + ((size_t)6 << 20));
  __bf16* w1T   = (__bf16*)(ws + ((size_t)8 << 20));
  __bf16* w2T   = (__bf16*)(ws + ((size_t)16 << 20));
  __bf16* qkbuf = (__bf16*)(ws + ((size_t)24 << 20));
  __bf16* vtbuf = (__bf16*)(ws + ((size_t)56 << 20));
  __bf16* abuf  = (__bf16*)(ws + ((size_t)72 << 20));
  float*  xbuf  = (float*) (ws + ((size_t)24 << 20));
  __bf16* ylnbuf= (__bf16*)(ws + ((size_t)56 << 20));
  __bf16* hbuf  = (__bf16*)(ws + ((size_t)72 << 20));
  float*  bqkv  = (float*) (ws + ((size_t)136 << 20));

  const dim3 blk(256);
  const dim3 blk8(512);
  prep_weights<<<12300, blk, 0, stream>>>(wq, wk, wv, wo, w1, w2, bq, bk, bv,
                                          wqkvT, woT, w1T, w2T, bqkv);

  ln_kernel<<<8192, blk, 0, stream>>>(input, ln1_g, ln1_b, abuf);
  // Q|K projection: gemm8, 256 blocks = exactly 1 pass at 1 block/CU
  gemm8_bt<EPI_QKV><<<dim3(8, 32), blk8, 0, stream>>>(abuf, wqkvT, bqkv,
                                                      qkbuf, vtbuf, 2048, 1024);
  // V projection: gemm_bt, 512 blocks at 2 blocks/CU
  gemm_bt<EPI_V><<<dim3(8, 64), blk, 0, stream>>>(abuf, wqkvT + (size_t)2048 * 1024,
                                                  bqkv + 2048, nullptr,
                                                  nullptr, vtbuf, 1024, 1024);
  attn_kernel<<<512, blk, 0, stream>>>(qkbuf, vtbuf, abuf);
  gemm_bt<EPI_RES><<<dim3(8, 64), blk, 0, stream>>>(abuf, woT, bo, input,
                                                    xbuf, nullptr, 1024, 1024);
  ln_kernel<<<8192, blk, 0, stream>>>(xbuf, ln2_g, ln2_b, ylnbuf);
  gemm8_bt<EPI_GELU><<<dim3(16, 32), blk8, 0, stream>>>(ylnbuf, w1T, b1,
                                                        hbuf, nullptr, 4096, 1024);
  gemm_bt<EPI_RES><<<dim3(8, 64), blk, 0, stream>>>(hbuf, w2T, b2, xbuf,
                                                    d_out, nullptr, 1024, 4096);
}

// Round 11
// 478.743 us; speedup vs baseline: 1.0168x; 1.0168x over previous
//
#include <hip/hip_runtime.h>
#include <hip/hip_bf16.h>

// EncoderBlock: LN1 -> MHA -> +res -> LN2 -> MLP(GELU exact) -> +res
// B=16 S=512 E=1024 F=4096 H=16 D=64, fp32 in/out, bf16 MFMA internally.
//
// R16: consolidation to measured-best + launch merge.
//  - gemm8_bt: R14-exact fenced 2-phase (R15's de-fence regressed 117->121,
//    VGPR 116->92 = compiler JIT-reads, less latency hiding -> reverted).
//    Schedule-invariance established: 4ph/2ph/unfenced all 117+-4 => this
//    256^2 K=1024 structure plateaus ~610 TF; stop tuning it.
//  - prep_weights + ln1 merged into one dispatch (prep_ln, grid 20492):
//    independent work, saves a launch gap + overlaps on-device.
//  - QKV split (QK gemm8 256blk / V gemm_bt), R10 attn + T5 setprio kept.
// Node forensics: w1 dur is the canary; ~204us @ ~700GB/s = throttled =
//   void round. hbm_gbps is self-referential (bytes const) - only the
//   throttle gap is diagnostic.
// Ledger (112-class): w1 112.6 | w2 ~105-110 | QK ~57-85 | attn ~55-70 |
//   V 33 | wo 33 | ln2 10 | prep+ln1 ~18 | gaps ~25.
//
// ws layout (bytes):
//   0        wqkvT  [3072][1024] bf16   6 MB   (wq^T|wk^T|wv^T)
//   6 MB     woT    [1024][1024] bf16   2 MB
//   8 MB     w1T    [4096][1024] bf16   8 MB
//   16 MB    w2T    [1024][4096] bf16   8 MB
//   24 MB    qk     [8192][2048] bf16  32 MB   (Q|K)   -> later x fp32 [8192][1024] 32 MB
//   56 MB    Vt     [256][64][512] bf16 16 MB          -> later y_ln bf16 16 MB
//   72 MB    abuf   [8192][1024] bf16  16 MB (ln1/attn)-> later h bf16 [8192][4096] 64 MB (72..136)
//   136 MB   bqkv   [3072] f32  12 KB

typedef __bf16 bf16x8 __attribute__((ext_vector_type(8)));
typedef __bf16 bf16x4 __attribute__((ext_vector_type(4)));
typedef float  f32x4  __attribute__((ext_vector_type(4)));

#define EPI_QKV  0
#define EPI_RES  1
#define EPI_GELU 2
#define EPI_V    3

__device__ __forceinline__ void async_copy16(const void* g, void* l) {
  __builtin_amdgcn_global_load_lds((const __attribute__((address_space(1))) void*)g,
                                   (__attribute__((address_space(3))) void*)l, 16, 0, 0);
}

// ---------------- layernorm helpers
__device__ __forceinline__ float block_sum(float v, float* red) {
#pragma unroll
  for (int off = 32; off; off >>= 1) v += __shfl_down(v, off);
  const int w = threadIdx.x >> 6;
  __syncthreads();
  if ((threadIdx.x & 63) == 0) red[w] = v;
  __syncthreads();
  return red[0] + red[1] + red[2] + red[3];
}

__device__ __forceinline__ void ln_row(const float* __restrict__ x,
                                       const float* __restrict__ g,
                                       const float* __restrict__ bta,
                                       __bf16* __restrict__ out, int row,
                                       float* red) {
  const int t = threadIdx.x;
  const float4 v = ((const float4*)(x + (size_t)row * 1024))[t];
  float s = v.x + v.y + v.z + v.w;
  s = block_sum(s, red);
  const float mean = s * (1.0f / 1024.0f);
  const float d0 = v.x - mean, d1 = v.y - mean, d2 = v.z - mean, d3 = v.w - mean;
  float vs = d0 * d0 + d1 * d1 + d2 * d2 + d3 * d3;
  vs = block_sum(vs, red);
  const float rstd = rsqrtf(vs * (1.0f / 1024.0f) + 1e-5f);
  const float4 gg = ((const float4*)g)[t];
  const float4 bb = ((const float4*)bta)[t];
  bf16x4 o;
  o[0] = (__bf16)(d0 * rstd * gg.x + bb.x);
  o[1] = (__bf16)(d1 * rstd * gg.y + bb.y);
  o[2] = (__bf16)(d2 * rstd * gg.z + bb.z);
  o[3] = (__bf16)(d3 * rstd * gg.w + bb.w);
  ((bf16x4*)out)[(size_t)row * 256 + t] = o;
}

__global__ __launch_bounds__(256) void ln_kernel(const float* __restrict__ x,
                                                 const float* __restrict__ g,
                                                 const float* __restrict__ bta,
                                                 __bf16* __restrict__ out) {
  __shared__ float red[8];
  ln_row(x, g, bta, out, blockIdx.x, red);
}

// ---------------- fused weight prep (6 transposes + bias concat) + LN1.
// bids 0..12287: weight transpose tiles; 12288..12299: bias concat;
// 12300..20491: LN1 rows (independent of prep -> safe to co-dispatch).
__global__ __launch_bounds__(256) void prep_ln(
    const float* __restrict__ wq, const float* __restrict__ wk,
    const float* __restrict__ wv, const float* __restrict__ wo,
    const float* __restrict__ w1, const float* __restrict__ w2,
    const float* __restrict__ bq, const float* __restrict__ bk,
    const float* __restrict__ bv,
    __bf16* __restrict__ wqkvT, __bf16* __restrict__ woT,
    __bf16* __restrict__ w1T, __bf16* __restrict__ w2T, float* __restrict__ bqkv,
    const float* __restrict__ input, const float* __restrict__ ln1_g,
    const float* __restrict__ ln1_b, __bf16* __restrict__ lnout) {
  const int bid = blockIdx.x;
  if (bid >= 12300) { // LN1 row
    __shared__ float red[8];
    ln_row(input, ln1_g, ln1_b, lnout, bid - 12300, red);
    return;
  }
  if (bid >= 12288) { // 12 bias blocks -> 3072 elements
    const int i = (bid - 12288) * 256 + threadIdx.x;
    bqkv[i] = (i < 1024) ? bq[i] : ((i < 2048) ? bk[i - 1024] : bv[i - 2048]);
    return;
  }
  const float* in;
  __bf16* out;
  int K, N, tile;
  if (bid < 4096) { // four 1024x1024 weights, 1024 tiles (32x32) each
    const int w = bid >> 10;
    tile = bid & 1023;
    in = (w == 0) ? wq : (w == 1) ? wk : (w == 2) ? wv : wo;
    out = (w == 3) ? woT : (wqkvT + (size_t)w * 1024 * 1024);
    K = 1024; N = 1024;
  } else if (bid < 8192) { tile = bid - 4096; in = w1; out = w1T; K = 1024; N = 4096; }
  else                   { tile = bid - 8192; in = w2; out = w2T; K = 4096; N = 1024; }
  const int ntx = N >> 5;
  const int bx = tile % ntx, by = tile / ntx;
  const int n0 = bx * 32, k0 = by * 32;

  __shared__ float tilebuf[32][33];
  const int tx = threadIdx.x & 31, ty = threadIdx.x >> 5; // 32x8
#pragma unroll
  for (int i = 0; i < 4; i++)
    tilebuf[ty + i * 8][tx] = in[(size_t)(k0 + ty + i * 8) * N + n0 + tx];
  __syncthreads();
#pragma unroll
  for (int i = 0; i < 4; i++)
    out[(size_t)(n0 + ty + i * 8) * K + k0 + tx] = (__bf16)tilebuf[tx][ty + i * 8];
}

// ---------------- GEMM 128x128 (R5-exact): C[8192][N] = A(bf16) * Bt^T + bias
// Single-buffered 32 KiB LDS -> ~3.4 blocks/CU; cross-block TLP hides the
// staging drain. XOR-swizzled LDS (0 conflicts), 16x16x32 MFMA, (256,2).
template <int EPI>
__global__ __launch_bounds__(256, 2) void gemm_bt(const __bf16* __restrict__ A,
                                                  const __bf16* __restrict__ Bt,
                                                  const float* __restrict__ bias,
                                                  const float* __restrict__ res,
                                                  void* __restrict__ out,
                                                  void* __restrict__ out2,
                                                  int N, int K) {
  __shared__ __bf16 lA[128 * 64];
  __shared__ __bf16 lB[128 * 64];
  const int t = threadIdx.x;
  const int wave = t >> 6, lane = t & 63;
  const int lm = lane & 15, lq = lane >> 4;

  // XCD-aware tile mapping (Mtiles = 64, divisible by 8)
  const int Ntiles = gridDim.x;
  const int flat = blockIdx.y * Ntiles + blockIdx.x;
  const int xcd = flat & 7;
  const int local = flat >> 3;
  const int tn = local % Ntiles;
  const int tm = (local / Ntiles) * 8 + xcd;
  const int m0 = tm * 128, n0 = tn * 128;
  const int wm = (wave & 1) * 64, wn = (wave >> 1) * 64;

  f32x4 acc[4][4] = {};

  const int srow = t >> 3, sslot = t & 7;
  const int schunk = sslot ^ (srow & 7);
  const __bf16* aSrc = A + (size_t)(m0 + srow) * K + schunk * 8;
  const __bf16* bSrc = Bt + (size_t)(n0 + srow) * K + schunk * 8;

  for (int k0 = 0; k0 < K; k0 += 64) {
#pragma unroll
    for (int i = 0; i < 4; i++) {
      async_copy16(aSrc + (size_t)(i * 32) * K, lA + i * 2048 + t * 8);
      async_copy16(bSrc + (size_t)(i * 32) * K, lB + i * 2048 + t * 8);
    }
    aSrc += 64; bSrc += 64;
    __syncthreads();
#pragma unroll
    for (int kk = 0; kk < 2; kk++) {
      bf16x8 af[4], bf[4];
      const int slot = (kk * 4 + lq) ^ (lm & 7); // frag row&7 == lm&7
#pragma unroll
      for (int i = 0; i < 4; i++) {
        af[i] = *(const bf16x8*)&lA[(wm + i * 16 + lm) * 64 + slot * 8];
        bf[i] = *(const bf16x8*)&lB[(wn + i * 16 + lm) * 64 + slot * 8];
      }
#pragma unroll
      for (int mi = 0; mi < 4; mi++)
#pragma unroll
        for (int ni = 0; ni < 4; ni++)
          acc[mi][ni] = __builtin_amdgcn_mfma_f32_16x16x32_bf16(af[mi], bf[ni], acc[mi][ni], 0, 0, 0);
    }
    __syncthreads();
  }

  // epilogue. C/D layout: col = lane&15, row = (lane>>4)*4 + reg  [m89/m91]
#pragma unroll
  for (int mi = 0; mi < 4; mi++) {
    const int gr = m0 + wm + mi * 16 + lq * 4;
#pragma unroll
    for (int ni = 0; ni < 4; ni++) {
      const int gc = n0 + wn + ni * 16 + lm;
      const float bv = bias[gc];
#pragma unroll
      for (int r = 0; r < 4; r++) {
        float v = acc[mi][ni][r] + bv;
        const int row = gr + r;
        if (EPI == EPI_GELU) {
          v = 0.5f * v * (1.0f + erff(v * 0.70710678118654752f));
          ((__bf16*)out)[(size_t)row * N + gc] = (__bf16)v;
        } else if (EPI == EPI_RES) {
          ((float*)out)[(size_t)row * N + gc] = v + res[(size_t)row * N + gc];
        } else if (EPI == EPI_V) { // V -> Vt[b][h][d][s]; gc in 0..1023
          const int d = gc & 63, hh = gc >> 6;
          const int bb = row >> 9, ss = row & 511;
          ((__bf16*)out2)[(((size_t)bb * 16 + hh) * 64 + d) * 512 + ss] = (__bf16)v;
        } else { // EPI_QKV: Q|K -> qk[8192][2048]; V -> Vt[b][h][d][s]
          if (gc < 2048) {
            ((__bf16*)out)[(size_t)row * 2048 + gc] = (__bf16)v;
          } else {
            const int d = gc & 63, hh = (gc - 2048) >> 6;
            const int bb = row >> 9, ss = row & 511;
            ((__bf16*)out2)[(((size_t)bb * 16 + hh) * 64 + d) * 512 + ss] = (__bf16)v;
          }
        }
      }
    }
  }
}

// ---------------- GEMM 256x256, 2-merged-phase pipelined (R14-exact). 512 thr
// / 8 waves (2Mx4N), wave tile 128x64, LDS 128 KiB double-buffered.
// Per K-tile: phase A {read B(8)+A01(8); stage B0,B1(t+1); bar; lgkm0;
// 32 MFMA; bar}, phase B {read A23(8); bar; lgkm0; 32 MFMA; bar},
// boundary {stage A(t+2); vmcnt(4); bar}. vmcnt(0) only at NT-2.
#define MFMA_QUAD(MI0)                                                         \
  do {                                                                         \
    _Pragma("unroll") for (int kk = 0; kk < 2; ++kk) {                         \
      _Pragma("unroll") for (int ni = 0; ni < 4; ++ni) {                       \
        acc[MI0][ni] = __builtin_amdgcn_mfma_f32_16x16x32_bf16(                \
            af[MI0][kk], bf[ni][kk], acc[MI0][ni], 0, 0, 0);                   \
        acc[(MI0) + 1][ni] = __builtin_amdgcn_mfma_f32_16x16x32_bf16(          \
            af[(MI0) + 1][kk], bf[ni][kk], acc[(MI0) + 1][ni], 0, 0, 0);       \
      }                                                                        \
    }                                                                          \
  } while (0)

#define READ_A8(MI)                                                            \
  _Pragma("unroll") for (int kk = 0; kk < 2; ++kk)                             \
      af[MI][kk] = *(const bf16x8*)&bufA[(wm * 128 + (MI)*16 + lm) * 64 +      \
                                         (((kk * 4 + lq) ^ sw) * 8)];

template <int EPI>
__global__ __launch_bounds__(512, 2) void gemm8_bt(const __bf16* __restrict__ A,
                                                   const __bf16* __restrict__ Bt,
                                                   const float* __restrict__ bias,
                                                   void* __restrict__ out,
                                                   void* __restrict__ out2,
                                                   int N, int K) {
  __shared__ __bf16 lA[2 * 256 * 64];
  __shared__ __bf16 lB[2 * 256 * 64];
  const int t = threadIdx.x;
  const int wave = t >> 6, lane = t & 63;
  const int lm = lane & 15, lq = lane >> 4, sw = lm & 7;
  const int wm = wave >> 2, wn = wave & 3;

  const int Ntiles = gridDim.x;
  const int flat = blockIdx.y * Ntiles + blockIdx.x;
  const int xcd = flat & 7;
  const int local = flat >> 3;
  const int tn = local % Ntiles;
  const int tm = (local / Ntiles) * 8 + xcd;
  const int m0 = tm * 256, n0 = tn * 256;

  const int NT = K >> 6;

  const int srow = t >> 3;
  const int schunk = (t & 7) ^ (srow & 7);
  const __bf16* aBase = A + (size_t)(m0 + srow) * K + schunk * 8;
  const __bf16* bBase = Bt + (size_t)(n0 + srow) * K + schunk * 8;
  __bf16* ldA = lA + t * 8;
  __bf16* ldB = lB + t * 8;

  auto stage = [&](int h) {
    if (h >= 4 * NT) return;
    const int tau = h >> 2, type = h & 3, hf = type & 1;
    const size_t roff = (size_t)(hf * 128) * K + (size_t)tau * 64;
    const int loff = (tau & 1) * 16384 + hf * 8192;
    if (type < 2) {
      async_copy16(aBase + roff, ldA + loff);
      async_copy16(aBase + roff + (size_t)64 * K, ldA + loff + 4096);
    } else {
      async_copy16(bBase + roff, ldB + loff);
      async_copy16(bBase + roff + (size_t)64 * K, ldB + loff + 4096);
    }
  };

  f32x4 acc[8][4] = {};

  // prologue: tile0 fully + A(1); vmcnt(4) leaves A(1) in flight
  for (int h = 0; h < 6; ++h) stage(h);
  asm volatile("s_waitcnt vmcnt(4)" ::: "memory");
  __builtin_amdgcn_s_barrier();

  for (int tt = 0; tt < NT; ++tt) {
    const __bf16* bufA = lA + (tt & 1) * 16384;
    const __bf16* bufB = lB + (tt & 1) * 16384;
    bf16x8 af[8][2], bf[4][2];

    // ---- phase A: read all B (8) + A quads 0-1 (8); stage B0,B1(t+1)
#pragma unroll
    for (int ni = 0; ni < 4; ++ni)
#pragma unroll
      for (int kk = 0; kk < 2; ++kk)
        bf[ni][kk] = *(const bf16x8*)&bufB[(wn * 64 + ni * 16 + lm) * 64 +
                                           (((kk * 4 + lq) ^ sw) * 8)];
    READ_A8(0)
    READ_A8(1)
    READ_A8(2)
    READ_A8(3)
    stage(4 * tt + 6); // B0(t+1) -> other buffer (WAR-safe: last read t-1)
    stage(4 * tt + 7); // B1(t+1)
    __builtin_amdgcn_s_barrier();
    asm volatile("s_waitcnt lgkmcnt(0)" ::: "memory");
    __builtin_amdgcn_sched_barrier(0);
    __builtin_amdgcn_s_setprio(1);
    MFMA_QUAD(0);
    MFMA_QUAD(2);
    __builtin_amdgcn_s_setprio(0);
    __builtin_amdgcn_s_barrier();

    // ---- phase B: read A quads 2-3 (8)
    READ_A8(4)
    READ_A8(5)
    READ_A8(6)
    READ_A8(7)
    __builtin_amdgcn_s_barrier();
    asm volatile("s_waitcnt lgkmcnt(0)" ::: "memory");
    __builtin_amdgcn_sched_barrier(0);
    __builtin_amdgcn_s_setprio(1);
    MFMA_QUAD(4);
    MFMA_QUAD(6);
    __builtin_amdgcn_s_setprio(0);
    __builtin_amdgcn_s_barrier(); // all A reads of buf(t) confirmed done

    // ---- boundary: stage A(t+2) into current (now-idle) A buffer
    if (tt < NT - 1) {
      stage(4 * tt + 8);
      stage(4 * tt + 9);
      if (tt == NT - 2) asm volatile("s_waitcnt vmcnt(0)" ::: "memory");
      else              asm volatile("s_waitcnt vmcnt(4)" ::: "memory");
      __builtin_amdgcn_s_barrier();
    }
  }

  // epilogue. C/D layout: col = lane&15, row = (lane>>4)*4 + reg
#pragma unroll
  for (int mi = 0; mi < 8; ++mi) {
    const int gr = m0 + wm * 128 + mi * 16 + lq * 4;
#pragma unroll
    for (int ni = 0; ni < 4; ++ni) {
      const int gc = n0 + wn * 64 + ni * 16 + lm;
      const float bv = bias[gc];
#pragma unroll
      for (int r = 0; r < 4; ++r) {
        float v = acc[mi][ni][r] + bv;
        const int row = gr + r;
        if (EPI == EPI_GELU) {
          v = 0.5f * v * (1.0f + erff(v * 0.70710678118654752f));
          ((__bf16*)out)[(size_t)row * N + gc] = (__bf16)v;
        } else { // EPI_QKV here: used with N=2048 (Q|K only) -> gc < 2048
          if (gc < 2048) {
            ((__bf16*)out)[(size_t)row * 2048 + gc] = (__bf16)v;
          } else {
            const int d = gc & 63, hh = (gc - 2048) >> 6;
            const int bb = row >> 9, ss = row & 511;
            ((__bf16*)out2)[(((size_t)bb * 16 + hh) * 64 + d) * 512 + ss] = (__bf16)v;
          }
        }
      }
    }
  }
}

// ---------------- flash attention (R10 + T5 setprio): 512 blocks (2/CU),
// block = (b, h, 256 q-rows), 4 waves x 64 q-rows (4 static groups of 16).
// K/V double-buffered (80 KiB LDS), counted vmcnt(8) staging.
__global__ __launch_bounds__(256, 2) void attn_kernel(const __bf16* __restrict__ qk,
                                                      const __bf16* __restrict__ Vt,
                                                      __bf16* __restrict__ outA) {
  __shared__ __bf16 lK[2][128 * 64];  // [key][d], 16B chunks XOR'd by key&7
  __shared__ __bf16 lV[2][64 * 128];  // [d][key], 16B chunks XOR'd by d&7
  __shared__ __bf16 lP[4][16 * 128];  // per-wave P, chunks XOR'd by q&7
  const int t = threadIdx.x, wave = t >> 6, lane = t & 63;
  const int lm = lane & 15, lq = lane >> 4;
  const int sw = lm & 7;
  const int flat = blockIdx.x;
  const int xcd = flat & 7, local = flat >> 3;
  const int qt = local & 1;
  const int bh = xcd * 32 + (local >> 1);
  const int h = bh & 15, b = bh >> 4;
  const int qbase = qt * 256 + wave * 64; // block covers 256 q-rows; wave 64

  // Q A-operand frags for 4 groups of 16 rows
  bf16x8 aq[4][2];
#pragma unroll
  for (int qg = 0; qg < 4; qg++) {
    const size_t qrow = (size_t)(b * 512 + qbase + qg * 16 + lm) * 2048 + h * 64;
    aq[qg][0] = *(const bf16x8*)&qk[qrow + lq * 8];
    aq[qg][1] = *(const bf16x8*)&qk[qrow + 32 + lq * 8];
  }

  float mrow[4][4], lrow[4][4];
  f32x4 o[4][4] = {};
#pragma unroll
  for (int qg = 0; qg < 4; qg++)
#pragma unroll
    for (int r = 0; r < 4; r++) { mrow[qg][r] = -3e38f; lrow[qg][r] = 0.f; }

  const int krow = t >> 3;
  const int kchunk = (t & 7) ^ (krow & 7);
  const __bf16* kSrc = qk + (size_t)(b * 512 + krow) * 2048 + 1024 + h * 64 + kchunk * 8;
  const int vrow = t >> 4;
  const int vchunk = (t & 15) ^ (vrow & 7);
  const __bf16* vSrc = Vt + ((size_t)bh * 64 + vrow) * 512 + vchunk * 8;

  auto stage = [&](int kt) {
    __bf16* dK = &lK[kt & 1][t * 8];
    __bf16* dV = &lV[kt & 1][t * 8];
#pragma unroll
    for (int i = 0; i < 4; i++) {
      async_copy16(kSrc + (size_t)(kt * 128 + i * 32) * 2048, dK + i * 2048);
      async_copy16(vSrc + kt * 128 + (size_t)(i * 16) * 512, dV + i * 2048);
    }
  };

  stage(0);
  for (int kt = 0; kt < 4; kt++) {
    if (kt < 3) {
      stage(kt + 1); // other buffer; its readers finished before last iter's end barrier
      asm volatile("s_waitcnt vmcnt(8)" ::: "memory"); // kt's 8 loads done; kt+1's in flight
    } else {
      asm volatile("s_waitcnt vmcnt(0)" ::: "memory");
    }
    __builtin_amdgcn_s_barrier(); // all waves' kt loads landed
    const __bf16* bK = lK[kt & 1];
    const __bf16* bV = lV[kt & 1];

#pragma unroll
    for (int qg = 0; qg < 4; qg++) {
      // S = Q K^T  (16 q x 128 keys)
      f32x4 s[8];
      __builtin_amdgcn_s_setprio(1);
#pragma unroll
      for (int ni = 0; ni < 8; ni++) {
        bf16x8 bk0 = *(const bf16x8*)&bK[(ni * 16 + lm) * 64 + ((lq ^ sw) * 8)];
        bf16x8 bk1 = *(const bf16x8*)&bK[(ni * 16 + lm) * 64 + (((4 + lq) ^ sw) * 8)];
        f32x4 z = {};
        z = __builtin_amdgcn_mfma_f32_16x16x32_bf16(aq[qg][0], bk0, z, 0, 0, 0);
        z = __builtin_amdgcn_mfma_f32_16x16x32_bf16(aq[qg][1], bk1, z, 0, 0, 0);
        s[ni] = z;
      }
      __builtin_amdgcn_s_setprio(0);
#pragma unroll
      for (int ni = 0; ni < 8; ni++)
#pragma unroll
        for (int r = 0; r < 4; r++) s[ni][r] *= 0.125f; // 1/sqrt(64)

      // online softmax; 16 lanes (one quad-row group) share each row
      float mnew[4], alpha[4];
#pragma unroll
      for (int r = 0; r < 4; r++) {
        float mx = s[0][r];
#pragma unroll
        for (int ni = 1; ni < 8; ni++) mx = fmaxf(mx, s[ni][r]);
#pragma unroll
        for (int off = 1; off < 16; off <<= 1) mx = fmaxf(mx, __shfl_xor(mx, off));
        mnew[r] = fmaxf(mrow[qg][r], mx);
        alpha[r] = __expf(mrow[qg][r] - mnew[r]);
        mrow[qg][r] = mnew[r];
      }
      float rs[4] = {0.f, 0.f, 0.f, 0.f};
#pragma unroll
      for (int ni = 0; ni < 8; ni++)
#pragma unroll
        for (int r = 0; r < 4; r++) {
          const float p = __expf(s[ni][r] - mnew[r]);
          s[ni][r] = p;
          rs[r] += p;
        }
#pragma unroll
      for (int r = 0; r < 4; r++) {
#pragma unroll
        for (int off = 1; off < 16; off <<= 1) rs[r] += __shfl_xor(rs[r], off);
        lrow[qg][r] = lrow[qg][r] * alpha[r] + rs[r];
      }

      // P: C-layout -> A-operand layout via per-wave LDS round trip, XOR'd by q&7
#pragma unroll
      for (int ni = 0; ni < 8; ni++) {
        const int chunk = ni * 2 + (lm >> 3);
#pragma unroll
        for (int r = 0; r < 4; r++) {
          const int q = lq * 4 + r;
          lP[wave][q * 128 + ((chunk ^ (q & 7)) * 8) + (lm & 7)] = (__bf16)s[ni][r];
        }
      }
      asm volatile("s_waitcnt lgkmcnt(0)" ::: "memory");
      bf16x8 ap[4];
#pragma unroll
      for (int kc = 0; kc < 4; kc++)
        ap[kc] = *(const bf16x8*)&lP[wave][lm * 128 + (((kc * 4 + lq) ^ sw) * 8)];

#pragma unroll
      for (int di = 0; di < 4; di++)
#pragma unroll
        for (int r = 0; r < 4; r++) o[qg][di][r] *= alpha[r];

      // O += P V ; B-operand n = d (lV[d][key], key contiguous, XOR'd by d&7)
      __builtin_amdgcn_s_setprio(1);
#pragma unroll
      for (int di = 0; di < 4; di++) {
#pragma unroll
        for (int kc = 0; kc < 4; kc++) {
          bf16x8 bv = *(const bf16x8*)&bV[(di * 16 + lm) * 128 + (((kc * 4 + lq) ^ sw) * 8)];
          o[qg][di] = __builtin_amdgcn_mfma_f32_16x16x32_bf16(ap[kc], bv, o[qg][di], 0, 0, 0);
        }
      }
      __builtin_amdgcn_s_setprio(0);
    }
    __builtin_amdgcn_s_barrier(); // all reads of buf[kt&1] done before next stage overwrites
  }

#pragma unroll
  for (int qg = 0; qg < 4; qg++)
#pragma unroll
    for (int di = 0; di < 4; di++)
#pragma unroll
      for (int r = 0; r < 4; r++) {
        const float v = o[qg][di][r] / lrow[qg][r];
        outA[(size_t)(b * 512 + qbase + qg * 16 + lq * 4 + r) * 1024 + h * 64 + di * 16 + lm] = (__bf16)v;
      }
}

extern "C" void kernel_launch(void* const* d_in, const int* in_sizes, int n_in,
                              void* d_out, int out_size, void* d_ws, size_t ws_size,
                              hipStream_t stream) {
  const float* input = (const float*)d_in[0];
  const float* ln1_g = (const float*)d_in[1];
  const float* ln1_b = (const float*)d_in[2];
  const float* wq = (const float*)d_in[3];
  const float* bq = (const float*)d_in[4];
  const float* wk = (const float*)d_in[5];
  const float* bk = (const float*)d_in[6];
  const float* wv = (const float*)d_in[7];
  const float* bv = (const float*)d_in[8];
  const float* wo = (const float*)d_in[9];
  const float* bo = (const float*)d_in[10];
  const float* ln2_g = (const float*)d_in[11];
  const float* ln2_b = (const float*)d_in[12];
  const float* w1 = (const float*)d_in[13];
  const float* b1 = (const float*)d_in[14];
  const float* w2 = (const float*)d_in[15];
  const float* b2 = (const float*)d_in[16];

  char* ws = (char*)d_ws;
  __bf16* wqkvT = (__bf16*)(ws + 0);
  __bf16* woT   = (__bf16*)(ws + ((size_t)6 << 20));
  __bf16* w1T   = (__bf16*)(ws + ((size_t)8 << 20));
  __bf16* w2T   = (__bf16*)(ws + ((size_t)16 << 20));
  __bf16* qkbuf = (__bf16*)(ws + ((size_t)24 << 20));
  __bf16* vtbuf = (__bf16*)(ws + ((size_t)56 << 20));
  __bf16* abuf  = (__bf16*)(ws + ((size_t)72 << 20));
  float*  xbuf  = (float*) (ws + ((size_t)24 << 20));
  __bf16* ylnbuf= (__bf16*)(ws + ((size_t)56 << 20));
  __bf16* hbuf  = (__bf16*)(ws + ((size_t)72 << 20));
  float*  bqkv  = (float*) (ws + ((size_t)136 << 20));

  const dim3 blk(256);
  const dim3 blk8(512);
  // fused weight prep + LN1 (independent work, one dispatch)
  prep_ln<<<20492, blk, 0, stream>>>(wq, wk, wv, wo, w1, w2, bq, bk, bv,
                                     wqkvT, woT, w1T, w2T, bqkv,
                                     input, ln1_g, ln1_b, abuf);
  // Q|K projection: gemm8, 256 blocks = exactly 1 pass at 1 block/CU
  gemm8_bt<EPI_QKV><<<dim3(8, 32), blk8, 0, stream>>>(abuf, wqkvT, bqkv,
                                                      qkbuf, vtbuf, 2048, 1024);
  // V projection: gemm_bt, 512 blocks at 2 blocks/CU
  gemm_bt<EPI_V><<<dim3(8, 64), blk, 0, stream>>>(abuf, wqkvT + (size_t)2048 * 1024,
                                                  bqkv + 2048, nullptr,
                                                  nullptr, vtbuf, 1024, 1024);
  attn_kernel<<<512, blk, 0, stream>>>(qkbuf, vtbuf, abuf);
  gemm_bt<EPI_RES><<<dim3(8, 64), blk, 0, stream>>>(abuf, woT, bo, input,
                                                    xbuf, nullptr, 1024, 1024);
  ln_kernel<<<8192, blk, 0, stream>>>(xbuf, ln2_g, ln2_b, ylnbuf);
  gemm8_bt<EPI_GELU><<<dim3(16, 32), blk8, 0, stream>>>(ylnbuf, w1T, b1,
                                                        hbuf, nullptr, 4096, 1024);
  gemm_bt<EPI_RES><<<dim3(8, 64), blk, 0, stream>>>(hbuf, w2T, b2, xbuf,
                                                    d_out, nullptr, 1024, 4096);
}

// Round 12
// 473.005 us; speedup vs baseline: 1.0291x; 1.0121x over previous
//
#include <hip/hip_runtime.h>
#include <hip/hip_bf16.h>

// EncoderBlock: LN1 -> MHA -> +res -> LN2 -> MLP(GELU exact) -> +res
// B=16 S=512 E=1024 F=4096 H=16 D=64, fp32 in/out, bf16 MFMA internally.
//
// R17 (base R16 = session best 478.7, twice-reproduced): attention swapped
//   QK^T. mfma(K,Q) instead of mfma(Q,K) (A/B frags have identical lane
//   structure -> argument swap only). P lands as P[q=lm][key=16ni+4lq+r]:
//   - softmax row stats become per-lane 32-reg tree + 2 shfl_xor (was 32
//     shfl per qg); mrow/lrow become per-lane scalars (-24 VGPR).
//   - P-write: 8x ds_write_b64 (4 consecutive keys of own row) vs 32x
//     ds_write_b16. 8B-chunk XOR swizzle by q&6 (even XOR keeps the b128
//     read pairs contiguous+aligned; ~4-way conflicts).
//   - alpha/lrow redistributed to o-layout via 4 __shfl (src lane lq*4+r).
//   Everything else byte-identical to R16. Predict attn 55 -> ~50,
//   total ~472-476 same node class. absmax must stay 0.03125; regression
//   or absmax failure -> revert attn next round.
// Plateau record: gemm8 {4ph,2ph,unfenced} all 117+-4; attn {2048blk,
//   512blk,+setprio} all ~55; stop tuning those structures.
// Node forensics: w1 dur is the canary (~112-117 healthy; ~204 = void).
//
// ws layout (bytes):
//   0        wqkvT  [3072][1024] bf16   6 MB   (wq^T|wk^T|wv^T)
//   6 MB     woT    [1024][1024] bf16   2 MB
//   8 MB     w1T    [4096][1024] bf16   8 MB
//   16 MB    w2T    [1024][4096] bf16   8 MB
//   24 MB    qk     [8192][2048] bf16  32 MB   (Q|K)   -> later x fp32 [8192][1024] 32 MB
//   56 MB    Vt     [256][64][512] bf16 16 MB          -> later y_ln bf16 16 MB
//   72 MB    abuf   [8192][1024] bf16  16 MB (ln1/attn)-> later h bf16 [8192][4096] 64 MB (72..136)
//   136 MB   bqkv   [3072] f32  12 KB

typedef __bf16 bf16x8 __attribute__((ext_vector_type(8)));
typedef __bf16 bf16x4 __attribute__((ext_vector_type(4)));
typedef float  f32x4  __attribute__((ext_vector_type(4)));

#define EPI_QKV  0
#define EPI_RES  1
#define EPI_GELU 2
#define EPI_V    3

__device__ __forceinline__ void async_copy16(const void* g, void* l) {
  __builtin_amdgcn_global_load_lds((const __attribute__((address_space(1))) void*)g,
                                   (__attribute__((address_space(3))) void*)l, 16, 0, 0);
}

// ---------------- layernorm helpers
__device__ __forceinline__ float block_sum(float v, float* red) {
#pragma unroll
  for (int off = 32; off; off >>= 1) v += __shfl_down(v, off);
  const int w = threadIdx.x >> 6;
  __syncthreads();
  if ((threadIdx.x & 63) == 0) red[w] = v;
  __syncthreads();
  return red[0] + red[1] + red[2] + red[3];
}

__device__ __forceinline__ void ln_row(const float* __restrict__ x,
                                       const float* __restrict__ g,
                                       const float* __restrict__ bta,
                                       __bf16* __restrict__ out, int row,
                                       float* red) {
  const int t = threadIdx.x;
  const float4 v = ((const float4*)(x + (size_t)row * 1024))[t];
  float s = v.x + v.y + v.z + v.w;
  s = block_sum(s, red);
  const float mean = s * (1.0f / 1024.0f);
  const float d0 = v.x - mean, d1 = v.y - mean, d2 = v.z - mean, d3 = v.w - mean;
  float vs = d0 * d0 + d1 * d1 + d2 * d2 + d3 * d3;
  vs = block_sum(vs, red);
  const float rstd = rsqrtf(vs * (1.0f / 1024.0f) + 1e-5f);
  const float4 gg = ((const float4*)g)[t];
  const float4 bb = ((const float4*)bta)[t];
  bf16x4 o;
  o[0] = (__bf16)(d0 * rstd * gg.x + bb.x);
  o[1] = (__bf16)(d1 * rstd * gg.y + bb.y);
  o[2] = (__bf16)(d2 * rstd * gg.z + bb.z);
  o[3] = (__bf16)(d3 * rstd * gg.w + bb.w);
  ((bf16x4*)out)[(size_t)row * 256 + t] = o;
}

__global__ __launch_bounds__(256) void ln_kernel(const float* __restrict__ x,
                                                 const float* __restrict__ g,
                                                 const float* __restrict__ bta,
                                                 __bf16* __restrict__ out) {
  __shared__ float red[8];
  ln_row(x, g, bta, out, blockIdx.x, red);
}

// ---------------- fused weight prep (6 transposes + bias concat) + LN1.
__global__ __launch_bounds__(256) void prep_ln(
    const float* __restrict__ wq, const float* __restrict__ wk,
    const float* __restrict__ wv, const float* __restrict__ wo,
    const float* __restrict__ w1, const float* __restrict__ w2,
    const float* __restrict__ bq, const float* __restrict__ bk,
    const float* __restrict__ bv,
    __bf16* __restrict__ wqkvT, __bf16* __restrict__ woT,
    __bf16* __restrict__ w1T, __bf16* __restrict__ w2T, float* __restrict__ bqkv,
    const float* __restrict__ input, const float* __restrict__ ln1_g,
    const float* __restrict__ ln1_b, __bf16* __restrict__ lnout) {
  const int bid = blockIdx.x;
  if (bid >= 12300) { // LN1 row
    __shared__ float red[8];
    ln_row(input, ln1_g, ln1_b, lnout, bid - 12300, red);
    return;
  }
  if (bid >= 12288) { // 12 bias blocks -> 3072 elements
    const int i = (bid - 12288) * 256 + threadIdx.x;
    bqkv[i] = (i < 1024) ? bq[i] : ((i < 2048) ? bk[i - 1024] : bv[i - 2048]);
    return;
  }
  const float* in;
  __bf16* out;
  int K, N, tile;
  if (bid < 4096) { // four 1024x1024 weights, 1024 tiles (32x32) each
    const int w = bid >> 10;
    tile = bid & 1023;
    in = (w == 0) ? wq : (w == 1) ? wk : (w == 2) ? wv : wo;
    out = (w == 3) ? woT : (wqkvT + (size_t)w * 1024 * 1024);
    K = 1024; N = 1024;
  } else if (bid < 8192) { tile = bid - 4096; in = w1; out = w1T; K = 1024; N = 4096; }
  else                   { tile = bid - 8192; in = w2; out = w2T; K = 4096; N = 1024; }
  const int ntx = N >> 5;
  const int bx = tile % ntx, by = tile / ntx;
  const int n0 = bx * 32, k0 = by * 32;

  __shared__ float tilebuf[32][33];
  const int tx = threadIdx.x & 31, ty = threadIdx.x >> 5; // 32x8
#pragma unroll
  for (int i = 0; i < 4; i++)
    tilebuf[ty + i * 8][tx] = in[(size_t)(k0 + ty + i * 8) * N + n0 + tx];
  __syncthreads();
#pragma unroll
  for (int i = 0; i < 4; i++)
    out[(size_t)(n0 + ty + i * 8) * K + k0 + tx] = (__bf16)tilebuf[tx][ty + i * 8];
}

// ---------------- GEMM 128x128 (R5-exact)
template <int EPI>
__global__ __launch_bounds__(256, 2) void gemm_bt(const __bf16* __restrict__ A,
                                                  const __bf16* __restrict__ Bt,
                                                  const float* __restrict__ bias,
                                                  const float* __restrict__ res,
                                                  void* __restrict__ out,
                                                  void* __restrict__ out2,
                                                  int N, int K) {
  __shared__ __bf16 lA[128 * 64];
  __shared__ __bf16 lB[128 * 64];
  const int t = threadIdx.x;
  const int wave = t >> 6, lane = t & 63;
  const int lm = lane & 15, lq = lane >> 4;

  const int Ntiles = gridDim.x;
  const int flat = blockIdx.y * Ntiles + blockIdx.x;
  const int xcd = flat & 7;
  const int local = flat >> 3;
  const int tn = local % Ntiles;
  const int tm = (local / Ntiles) * 8 + xcd;
  const int m0 = tm * 128, n0 = tn * 128;
  const int wm = (wave & 1) * 64, wn = (wave >> 1) * 64;

  f32x4 acc[4][4] = {};

  const int srow = t >> 3, sslot = t & 7;
  const int schunk = sslot ^ (srow & 7);
  const __bf16* aSrc = A + (size_t)(m0 + srow) * K + schunk * 8;
  const __bf16* bSrc = Bt + (size_t)(n0 + srow) * K + schunk * 8;

  for (int k0 = 0; k0 < K; k0 += 64) {
#pragma unroll
    for (int i = 0; i < 4; i++) {
      async_copy16(aSrc + (size_t)(i * 32) * K, lA + i * 2048 + t * 8);
      async_copy16(bSrc + (size_t)(i * 32) * K, lB + i * 2048 + t * 8);
    }
    aSrc += 64; bSrc += 64;
    __syncthreads();
#pragma unroll
    for (int kk = 0; kk < 2; kk++) {
      bf16x8 af[4], bf[4];
      const int slot = (kk * 4 + lq) ^ (lm & 7);
#pragma unroll
      for (int i = 0; i < 4; i++) {
        af[i] = *(const bf16x8*)&lA[(wm + i * 16 + lm) * 64 + slot * 8];
        bf[i] = *(const bf16x8*)&lB[(wn + i * 16 + lm) * 64 + slot * 8];
      }
#pragma unroll
      for (int mi = 0; mi < 4; mi++)
#pragma unroll
        for (int ni = 0; ni < 4; ni++)
          acc[mi][ni] = __builtin_amdgcn_mfma_f32_16x16x32_bf16(af[mi], bf[ni], acc[mi][ni], 0, 0, 0);
    }
    __syncthreads();
  }

  // epilogue. C/D layout: col = lane&15, row = (lane>>4)*4 + reg  [m89/m91]
#pragma unroll
  for (int mi = 0; mi < 4; mi++) {
    const int gr = m0 + wm + mi * 16 + lq * 4;
#pragma unroll
    for (int ni = 0; ni < 4; ni++) {
      const int gc = n0 + wn + ni * 16 + lm;
      const float bv = bias[gc];
#pragma unroll
      for (int r = 0; r < 4; r++) {
        float v = acc[mi][ni][r] + bv;
        const int row = gr + r;
        if (EPI == EPI_GELU) {
          v = 0.5f * v * (1.0f + erff(v * 0.70710678118654752f));
          ((__bf16*)out)[(size_t)row * N + gc] = (__bf16)v;
        } else if (EPI == EPI_RES) {
          ((float*)out)[(size_t)row * N + gc] = v + res[(size_t)row * N + gc];
        } else if (EPI == EPI_V) { // V -> Vt[b][h][d][s]; gc in 0..1023
          const int d = gc & 63, hh = gc >> 6;
          const int bb = row >> 9, ss = row & 511;
          ((__bf16*)out2)[(((size_t)bb * 16 + hh) * 64 + d) * 512 + ss] = (__bf16)v;
        } else { // EPI_QKV
          if (gc < 2048) {
            ((__bf16*)out)[(size_t)row * 2048 + gc] = (__bf16)v;
          } else {
            const int d = gc & 63, hh = (gc - 2048) >> 6;
            const int bb = row >> 9, ss = row & 511;
            ((__bf16*)out2)[(((size_t)bb * 16 + hh) * 64 + d) * 512 + ss] = (__bf16)v;
          }
        }
      }
    }
  }
}

// ---------------- GEMM 256x256, 2-merged-phase pipelined (R14-exact).
#define MFMA_QUAD(MI0)                                                         \
  do {                                                                         \
    _Pragma("unroll") for (int kk = 0; kk < 2; ++kk) {                         \
      _Pragma("unroll") for (int ni = 0; ni < 4; ++ni) {                       \
        acc[MI0][ni] = __builtin_amdgcn_mfma_f32_16x16x32_bf16(                \
            af[MI0][kk], bf[ni][kk], acc[MI0][ni], 0, 0, 0);                   \
        acc[(MI0) + 1][ni] = __builtin_amdgcn_mfma_f32_16x16x32_bf16(          \
            af[(MI0) + 1][kk], bf[ni][kk], acc[(MI0) + 1][ni], 0, 0, 0);       \
      }                                                                        \
    }                                                                          \
  } while (0)

#define READ_A8(MI)                                                            \
  _Pragma("unroll") for (int kk = 0; kk < 2; ++kk)                             \
      af[MI][kk] = *(const bf16x8*)&bufA[(wm * 128 + (MI)*16 + lm) * 64 +      \
                                         (((kk * 4 + lq) ^ sw) * 8)];

template <int EPI>
__global__ __launch_bounds__(512, 2) void gemm8_bt(const __bf16* __restrict__ A,
                                                   const __bf16* __restrict__ Bt,
                                                   const float* __restrict__ bias,
                                                   void* __restrict__ out,
                                                   void* __restrict__ out2,
                                                   int N, int K) {
  __shared__ __bf16 lA[2 * 256 * 64];
  __shared__ __bf16 lB[2 * 256 * 64];
  const int t = threadIdx.x;
  const int wave = t >> 6, lane = t & 63;
  const int lm = lane & 15, lq = lane >> 4, sw = lm & 7;
  const int wm = wave >> 2, wn = wave & 3;

  const int Ntiles = gridDim.x;
  const int flat = blockIdx.y * Ntiles + blockIdx.x;
  const int xcd = flat & 7;
  const int local = flat >> 3;
  const int tn = local % Ntiles;
  const int tm = (local / Ntiles) * 8 + xcd;
  const int m0 = tm * 256, n0 = tn * 256;

  const int NT = K >> 6;

  const int srow = t >> 3;
  const int schunk = (t & 7) ^ (srow & 7);
  const __bf16* aBase = A + (size_t)(m0 + srow) * K + schunk * 8;
  const __bf16* bBase = Bt + (size_t)(n0 + srow) * K + schunk * 8;
  __bf16* ldA = lA + t * 8;
  __bf16* ldB = lB + t * 8;

  auto stage = [&](int h) {
    if (h >= 4 * NT) return;
    const int tau = h >> 2, type = h & 3, hf = type & 1;
    const size_t roff = (size_t)(hf * 128) * K + (size_t)tau * 64;
    const int loff = (tau & 1) * 16384 + hf * 8192;
    if (type < 2) {
      async_copy16(aBase + roff, ldA + loff);
      async_copy16(aBase + roff + (size_t)64 * K, ldA + loff + 4096);
    } else {
      async_copy16(bBase + roff, ldB + loff);
      async_copy16(bBase + roff + (size_t)64 * K, ldB + loff + 4096);
    }
  };

  f32x4 acc[8][4] = {};

  // prologue: tile0 fully + A(1); vmcnt(4) leaves A(1) in flight
  for (int h = 0; h < 6; ++h) stage(h);
  asm volatile("s_waitcnt vmcnt(4)" ::: "memory");
  __builtin_amdgcn_s_barrier();

  for (int tt = 0; tt < NT; ++tt) {
    const __bf16* bufA = lA + (tt & 1) * 16384;
    const __bf16* bufB = lB + (tt & 1) * 16384;
    bf16x8 af[8][2], bf[4][2];

    // ---- phase A: read all B (8) + A quads 0-1 (8); stage B0,B1(t+1)
#pragma unroll
    for (int ni = 0; ni < 4; ++ni)
#pragma unroll
      for (int kk = 0; kk < 2; ++kk)
        bf[ni][kk] = *(const bf16x8*)&bufB[(wn * 64 + ni * 16 + lm) * 64 +
                                           (((kk * 4 + lq) ^ sw) * 8)];
    READ_A8(0)
    READ_A8(1)
    READ_A8(2)
    READ_A8(3)
    stage(4 * tt + 6); // B0(t+1) -> other buffer (WAR-safe: last read t-1)
    stage(4 * tt + 7); // B1(t+1)
    __builtin_amdgcn_s_barrier();
    asm volatile("s_waitcnt lgkmcnt(0)" ::: "memory");
    __builtin_amdgcn_sched_barrier(0);
    __builtin_amdgcn_s_setprio(1);
    MFMA_QUAD(0);
    MFMA_QUAD(2);
    __builtin_amdgcn_s_setprio(0);
    __builtin_amdgcn_s_barrier();

    // ---- phase B: read A quads 2-3 (8)
    READ_A8(4)
    READ_A8(5)
    READ_A8(6)
    READ_A8(7)
    __builtin_amdgcn_s_barrier();
    asm volatile("s_waitcnt lgkmcnt(0)" ::: "memory");
    __builtin_amdgcn_sched_barrier(0);
    __builtin_amdgcn_s_setprio(1);
    MFMA_QUAD(4);
    MFMA_QUAD(6);
    __builtin_amdgcn_s_setprio(0);
    __builtin_amdgcn_s_barrier(); // all A reads of buf(t) confirmed done

    // ---- boundary: stage A(t+2) into current (now-idle) A buffer
    if (tt < NT - 1) {
      stage(4 * tt + 8);
      stage(4 * tt + 9);
      if (tt == NT - 2) asm volatile("s_waitcnt vmcnt(0)" ::: "memory");
      else              asm volatile("s_waitcnt vmcnt(4)" ::: "memory");
      __builtin_amdgcn_s_barrier();
    }
  }

  // epilogue. C/D layout: col = lane&15, row = (lane>>4)*4 + reg
#pragma unroll
  for (int mi = 0; mi < 8; ++mi) {
    const int gr = m0 + wm * 128 + mi * 16 + lq * 4;
#pragma unroll
    for (int ni = 0; ni < 4; ++ni) {
      const int gc = n0 + wn * 64 + ni * 16 + lm;
      const float bv = bias[gc];
#pragma unroll
      for (int r = 0; r < 4; ++r) {
        float v = acc[mi][ni][r] + bv;
        const int row = gr + r;
        if (EPI == EPI_GELU) {
          v = 0.5f * v * (1.0f + erff(v * 0.70710678118654752f));
          ((__bf16*)out)[(size_t)row * N + gc] = (__bf16)v;
        } else { // EPI_QKV here: used with N=2048 (Q|K only) -> gc < 2048
          if (gc < 2048) {
            ((__bf16*)out)[(size_t)row * 2048 + gc] = (__bf16)v;
          } else {
            const int d = gc & 63, hh = (gc - 2048) >> 6;
            const int bb = row >> 9, ss = row & 511;
            ((__bf16*)out2)[(((size_t)bb * 16 + hh) * 64 + d) * 512 + ss] = (__bf16)v;
          }
        }
      }
    }
  }
}

// ---------------- flash attention R17: swapped QK^T (A=K, B=Q).
// P[q=lm][key=16ni+4lq+r] per lane -> per-lane softmax (32-reg tree + 2
// shfl_xor), b64 P-writes (8 per qg, chunk XOR q&6), alpha/lrow shfl
// redistribution. 512 blocks (2/CU), 4 waves x 64 q-rows, K/V dbuf,
// counted vmcnt(8) staging. All other machinery R16-identical.
__global__ __launch_bounds__(256, 2) void attn_kernel(const __bf16* __restrict__ qk,
                                                      const __bf16* __restrict__ Vt,
                                                      __bf16* __restrict__ outA) {
  __shared__ __bf16 lK[2][128 * 64];  // [key][d], 16B chunks XOR'd by key&7
  __shared__ __bf16 lV[2][64 * 128];  // [d][key], 16B chunks XOR'd by d&7
  __shared__ __bf16 lP[4][16 * 128];  // per-wave P[q][key], 8B chunks XOR'd by q&6
  const int t = threadIdx.x, wave = t >> 6, lane = t & 63;
  const int lm = lane & 15, lq = lane >> 4;
  const int sw = lm & 7;
  const int flat = blockIdx.x;
  const int xcd = flat & 7, local = flat >> 3;
  const int qt = local & 1;
  const int bh = xcd * 32 + (local >> 1);
  const int h = bh & 15, b = bh >> 4;
  const int qbase = qt * 256 + wave * 64; // block covers 256 q-rows; wave 64

  // Q fragments (serve as the B-operand after the swap; same lane layout)
  bf16x8 aq[4][2];
#pragma unroll
  for (int qg = 0; qg < 4; qg++) {
    const size_t qrow = (size_t)(b * 512 + qbase + qg * 16 + lm) * 2048 + h * 64;
    aq[qg][0] = *(const bf16x8*)&qk[qrow + lq * 8];
    aq[qg][1] = *(const bf16x8*)&qk[qrow + 32 + lq * 8];
  }

  // per-lane row stats for q = lm (one scalar per qg)
  float mrow[4], lrow[4];
  f32x4 o[4][4] = {};
#pragma unroll
  for (int qg = 0; qg < 4; qg++) { mrow[qg] = -3e38f; lrow[qg] = 0.f; }

  const int krow = t >> 3;
  const int kchunk = (t & 7) ^ (krow & 7);
  const __bf16* kSrc = qk + (size_t)(b * 512 + krow) * 2048 + 1024 + h * 64 + kchunk * 8;
  const int vrow = t >> 4;
  const int vchunk = (t & 15) ^ (vrow & 7);
  const __bf16* vSrc = Vt + ((size_t)bh * 64 + vrow) * 512 + vchunk * 8;

  auto stage = [&](int kt) {
    __bf16* dK = &lK[kt & 1][t * 8];
    __bf16* dV = &lV[kt & 1][t * 8];
#pragma unroll
    for (int i = 0; i < 4; i++) {
      async_copy16(kSrc + (size_t)(kt * 128 + i * 32) * 2048, dK + i * 2048);
      async_copy16(vSrc + kt * 128 + (size_t)(i * 16) * 512, dV + i * 2048);
    }
  };

  stage(0);
  for (int kt = 0; kt < 4; kt++) {
    if (kt < 3) {
      stage(kt + 1);
      asm volatile("s_waitcnt vmcnt(8)" ::: "memory");
    } else {
      asm volatile("s_waitcnt vmcnt(0)" ::: "memory");
    }
    __builtin_amdgcn_s_barrier();
    const __bf16* bK = lK[kt & 1];
    const __bf16* bV = lV[kt & 1];

#pragma unroll
    for (int qg = 0; qg < 4; qg++) {
      // S^T = K Q^T: lane holds P[q=lm][key = ni*16 + lq*4 + r]
      f32x4 s[8];
      __builtin_amdgcn_s_setprio(1);
#pragma unroll
      for (int ni = 0; ni < 8; ni++) {
        bf16x8 bk0 = *(const bf16x8*)&bK[(ni * 16 + lm) * 64 + ((lq ^ sw) * 8)];
        bf16x8 bk1 = *(const bf16x8*)&bK[(ni * 16 + lm) * 64 + (((4 + lq) ^ sw) * 8)];
        f32x4 z = {};
        z = __builtin_amdgcn_mfma_f32_16x16x32_bf16(bk0, aq[qg][0], z, 0, 0, 0);
        z = __builtin_amdgcn_mfma_f32_16x16x32_bf16(bk1, aq[qg][1], z, 0, 0, 0);
        s[ni] = z;
      }
      __builtin_amdgcn_s_setprio(0);
#pragma unroll
      for (int ni = 0; ni < 8; ni++)
#pragma unroll
        for (int r = 0; r < 4; r++) s[ni][r] *= 0.125f; // 1/sqrt(64)

      // per-lane online softmax for row q = lm (32 values in regs)
      float tmax[8];
#pragma unroll
      for (int ni = 0; ni < 8; ni++)
        tmax[ni] = fmaxf(fmaxf(s[ni][0], s[ni][1]), fmaxf(s[ni][2], s[ni][3]));
      float mx = fmaxf(fmaxf(fmaxf(tmax[0], tmax[1]), fmaxf(tmax[2], tmax[3])),
                       fmaxf(fmaxf(tmax[4], tmax[5]), fmaxf(tmax[6], tmax[7])));
      mx = fmaxf(mx, __shfl_xor(mx, 16));
      mx = fmaxf(mx, __shfl_xor(mx, 32));
      const float mnew = fmaxf(mrow[qg], mx);
      const float alpha = __expf(mrow[qg] - mnew);
      mrow[qg] = mnew;
      float rs = 0.f;
#pragma unroll
      for (int ni = 0; ni < 8; ni++)
#pragma unroll
        for (int r = 0; r < 4; r++) {
          const float p = __expf(s[ni][r] - mnew);
          s[ni][r] = p;
          rs += p;
        }
      rs += __shfl_xor(rs, 16);
      rs += __shfl_xor(rs, 32);
      lrow[qg] = lrow[qg] * alpha + rs;

      // P-store: row q=lm, 8B chunk (4ni+lq) XOR'd by (lm&6) -> b64 writes
#pragma unroll
      for (int ni = 0; ni < 8; ni++) {
        bf16x4 pw;
        pw[0] = (__bf16)s[ni][0];
        pw[1] = (__bf16)s[ni][1];
        pw[2] = (__bf16)s[ni][2];
        pw[3] = (__bf16)s[ni][3];
        *(bf16x4*)&lP[wave][lm * 128 + (((4 * ni + lq) ^ (lm & 6)) * 4)] = pw;
      }
      asm volatile("s_waitcnt lgkmcnt(0)" ::: "memory");
      // PV A-operand: keys kc*32+lq*8+{0..7} of row lm = stored chunks
      // {(8kc+2lq)^(lm&6), +1} (even XOR keeps the 16B pair contiguous)
      bf16x8 ap[4];
#pragma unroll
      for (int kc = 0; kc < 4; kc++)
        ap[kc] = *(const bf16x8*)&lP[wave][lm * 128 + (((8 * kc + 2 * lq) ^ (lm & 6)) * 4)];

      // redistribute alpha (per-lane, q=lm) to o-layout (q = lq*4+r)
      float alr[4];
#pragma unroll
      for (int r = 0; r < 4; r++) alr[r] = __shfl(alpha, lq * 4 + r);
#pragma unroll
      for (int di = 0; di < 4; di++)
#pragma unroll
        for (int r = 0; r < 4; r++) o[qg][di][r] *= alr[r];

      // O += P V
      __builtin_amdgcn_s_setprio(1);
#pragma unroll
      for (int di = 0; di < 4; di++) {
#pragma unroll
        for (int kc = 0; kc < 4; kc++) {
          bf16x8 bv = *(const bf16x8*)&bV[(di * 16 + lm) * 128 + (((kc * 4 + lq) ^ sw) * 8)];
          o[qg][di] = __builtin_amdgcn_mfma_f32_16x16x32_bf16(ap[kc], bv, o[qg][di], 0, 0, 0);
        }
      }
      __builtin_amdgcn_s_setprio(0);
    }
    __builtin_amdgcn_s_barrier(); // all reads of buf[kt&1] done before next stage overwrites
  }

#pragma unroll
  for (int qg = 0; qg < 4; qg++) {
    float lrq[4];
#pragma unroll
    for (int r = 0; r < 4; r++) lrq[r] = __shfl(lrow[qg], lq * 4 + r);
#pragma unroll
    for (int di = 0; di < 4; di++)
#pragma unroll
      for (int r = 0; r < 4; r++) {
        const float v = o[qg][di][r] / lrq[r];
        outA[(size_t)(b * 512 + qbase + qg * 16 + lq * 4 + r) * 1024 + h * 64 + di * 16 + lm] = (__bf16)v;
      }
  }
}

extern "C" void kernel_launch(void* const* d_in, const int* in_sizes, int n_in,
                              void* d_out, int out_size, void* d_ws, size_t ws_size,
                              hipStream_t stream) {
  const float* input = (const float*)d_in[0];
  const float* ln1_g = (const float*)d_in[1];
  const float* ln1_b = (const float*)d_in[2];
  const float* wq = (const float*)d_in[3];
  const float* bq = (const float*)d_in[4];
  const float* wk = (const float*)d_in[5];
  const float* bk = (const float*)d_in[6];
  const float* wv = (const float*)d_in[7];
  const float* bv = (const float*)d_in[8];
  const float* wo = (const float*)d_in[9];
  const float* bo = (const float*)d_in[10];
  const float* ln2_g = (const float*)d_in[11];
  const float* ln2_b = (const float*)d_in[12];
  const float* w1 = (const float*)d_in[13];
  const float* b1 = (const float*)d_in[14];
  const float* w2 = (const float*)d_in[15];
  const float* b2 = (const float*)d_in[16];

  char* ws = (char*)d_ws;
  __bf16* wqkvT = (__bf16*)(ws + 0);
  __bf16* woT   = (__bf16*)(ws + ((size_t)6 << 20));
  __bf16* w1T   = (__bf16*)(ws + ((size_t)8 << 20));
  __bf16* w2T   = (__bf16*)(ws + ((size_t)16 << 20));
  __bf16* qkbuf = (__bf16*)(ws + ((size_t)24 << 20));
  __bf16* vtbuf = (__bf16*)(ws + ((size_t)56 << 20));
  __bf16* abuf  = (__bf16*)(ws + ((size_t)72 << 20));
  float*  xbuf  = (float*) (ws + ((size_t)24 << 20));
  __bf16* ylnbuf= (__bf16*)(ws + ((size_t)56 << 20));
  __bf16* hbuf  = (__bf16*)(ws + ((size_t)72 << 20));
  float*  bqkv  = (float*) (ws + ((size_t)136 << 20));

  const dim3 blk(256);
  const dim3 blk8(512);
  // fused weight prep + LN1 (independent work, one dispatch)
  prep_ln<<<20492, blk, 0, stream>>>(wq, wk, wv, wo, w1, w2, bq, bk, bv,
                                     wqkvT, woT, w1T, w2T, bqkv,
                                     input, ln1_g, ln1_b, abuf);
  // Q|K projection: gemm8, 256 blocks = exactly 1 pass at 1 block/CU
  gemm8_bt<EPI_QKV><<<dim3(8, 32), blk8, 0, stream>>>(abuf, wqkvT, bqkv,
                                                      qkbuf, vtbuf, 2048, 1024);
  // V projection: gemm_bt, 512 blocks at 2 blocks/CU
  gemm_bt<EPI_V><<<dim3(8, 64), blk, 0, stream>>>(abuf, wqkvT + (size_t)2048 * 1024,
                                                  bqkv + 2048, nullptr,
                                                  nullptr, vtbuf, 1024, 1024);
  attn_kernel<<<512, blk, 0, stream>>>(qkbuf, vtbuf, abuf);
  gemm_bt<EPI_RES><<<dim3(8, 64), blk, 0, stream>>>(abuf, woT, bo, input,
                                                    xbuf, nullptr, 1024, 1024);
  ln_kernel<<<8192, blk, 0, stream>>>(xbuf, ln2_g, ln2_b, ylnbuf);
  gemm8_bt<EPI_GELU><<<dim3(16, 32), blk8, 0, stream>>>(ylnbuf, w1T, b1,
                                                        hbuf, nullptr, 4096, 1024);
  gemm_bt<EPI_RES><<<dim3(8, 64), blk, 0, stream>>>(hbuf, w2T, b2, xbuf,
                                                    d_out, nullptr, 1024, 4096);
}